// Round 14
// baseline (558.870 us; speedup 1.0000x reference)
//
#include <hip/hip_runtime.h>
#include <hip/hip_bf16.h>
#include <stdint.h>

#define B4 4096
#define KZ 1056   // padded z width: 1024 + 1 (ones col) + 31 pad (33 x 32)
#define KH 160    // padded hypernet-input width: 132 + 1 + pad

typedef short bf16x8 __attribute__((ext_vector_type(8)));
typedef float f32x4 __attribute__((ext_vector_type(4)));

__device__ __forceinline__ float b2f(uint16_t u){
  union {float f; uint32_t i;} v; v.i = ((uint32_t)u)<<16; return v.f;
}
__device__ __forceinline__ uint16_t f2b(float f){
  union {float fv; uint32_t i;} v; v.fv = f;
  uint32_t r = v.i + 0x7FFFu + ((v.i>>16)&1u);
  return (uint16_t)(r>>16);
}
__device__ __forceinline__ void gload16(const void* g, void* l){
  __builtin_amdgcn_global_load_lds(
      (__attribute__((address_space(1))) void*)(g),
      (__attribute__((address_space(3))) void*)(l), 16, 0, 0);
}

// ---------------------------------------------------------------------------
// Transpose tile body. dst[c][k] (bf16, K-contiguous) from src fp32
// [Ksrc][src_ld]; row k==Ksrc gets bias; k>Ksrc zero; din padding handled.
// ---------------------------------------------------------------------------
__device__ __forceinline__ void tp_tile(
    float (*tile)[33],
    const float* __restrict__ src, const float* __restrict__ bias,
    uint16_t* __restrict__ dst,
    int Ncols, int Kdst, int Ksrc, int src_ld, int din_dst, int din_src,
    int ct, int kt)
{
  int tid = threadIdx.x;
  int cl = tid & 31, kg = tid >> 5;
  #pragma unroll
  for (int r = 0; r < 4; ++r){
    int kl = kg*4 + r;
    int k  = kt*32 + kl;
    int c  = ct*32 + cl;
    float v = 0.f;
    if (c < Ncols){
      int o = c / din_dst, i = c - o*din_dst;
      if (i < din_src){
        int sc = o*din_src + i;
        if (k < Ksrc)       v = src[(size_t)k*src_ld + sc];
        else if (k == Ksrc) v = bias[sc];
      }
    }
    tile[kl][cl] = v;
  }
  __syncthreads();
  int c_loc = tid >> 3, kq = tid & 7;
  int c = ct*32 + c_loc;
  if (c < Ncols){
    ushort4 st;
    uint16_t* sp = (uint16_t*)&st;
    #pragma unroll
    for (int r = 0; r < 4; ++r) sp[r] = f2b(tile[kq*4 + r][c_loc]);
    *(ushort4*)&dst[(size_t)c*Kdst + kt*32 + kq*4] = st;
  }
}

// ---------------------------------------------------------------------------
// prep_small: everything the z1-GEMM / heads chain needs (small transposes +
// input packing + z pad init). Ranges: We1T 160 | We2T 1056 | WpT2 528 |
// bs 561 | misc 6656  => grid 8961.
// ---------------------------------------------------------------------------
__global__ __launch_bounds__(256) void prep_small(
    const float* __restrict__ We1, const float* __restrict__ be1,
    const float* __restrict__ We2, const float* __restrict__ be2,
    const float* __restrict__ Ww2, const float* __restrict__ bw2,
    const float* __restrict__ Wb0, const float* __restrict__ bb0,
    const float* __restrict__ Ws0, const float* __restrict__ bs0,
    const float* __restrict__ Wb1, const float* __restrict__ bb1,
    const float* __restrict__ Ws1, const float* __restrict__ bs1,
    const float* __restrict__ Wb2, const float* __restrict__ bb2,
    const float* __restrict__ Ws2, const float* __restrict__ bs2,
    const float* __restrict__ obs, const float* __restrict__ act,
    const float* __restrict__ prefs,
    uint16_t* __restrict__ We1T, uint16_t* __restrict__ We2T,
    uint16_t* __restrict__ WpT2, uint16_t* __restrict__ WbsT,
    uint16_t* __restrict__ Wbs2T,
    uint16_t* __restrict__ hinp, uint16_t* __restrict__ x0T,
    uint16_t* __restrict__ z1p, uint16_t* __restrict__ zp)
{
  __shared__ float tile[32][33];
  int bid = blockIdx.x;
  int tid = threadIdx.x;

  if (bid < 160){
    tp_tile(tile, We1, be1, We1T, 1024, KH, 132, 1024, 1024, 1024,
            bid % 32, bid / 32);
  } else if (bid < 1216){
    int b = bid - 160;
    tp_tile(tile, We2, be2, We2T, 1024, KZ, 1024, 1024, 1024, 1024,
            b % 32, b / 32);
  } else if (bid < 1744){
    int b = bid - 1216;
    tp_tile(tile, Ww2, bw2, WpT2, 512, KZ, 1024, 512, 128, 128,
            b % 16, b / 16);
  } else if (bid < 2305){
    // bias/scale heads: WbsT 512 cols (Wb0|Ws0|Wb1|Ws1), Wbs2T 8 cols
    int b = bid - 1744;
    int ct = b % 17, kt = b / 17;
    int cl = tid & 31, kg = tid >> 5;
    #pragma unroll
    for (int r = 0; r < 4; ++r){
      int kl = kg*4 + r;
      int k  = kt*32 + kl;
      int c  = ct*32 + cl;
      float v = 0.f;
      if (c < 512){
        int sel = c >> 7, sc = c & 127;
        const float* S  = (sel==0) ? Wb0 : (sel==1) ? Ws0 : (sel==2) ? Wb1 : Ws1;
        const float* Bs = (sel==0) ? bb0 : (sel==1) ? bs0 : (sel==2) ? bb1 : bs1;
        if (k < 1024)       v = S[(size_t)k*128 + sc];
        else if (k == 1024) v = Bs[sc];
      } else if (c < 520){
        int cc = c - 512;
        int sel = cc >> 2, sc = cc & 3;
        const float* S  = sel ? Ws2 : Wb2;
        const float* Bs = sel ? bs2 : bb2;
        if (k < 1024)       v = S[(size_t)k*4 + sc];
        else if (k == 1024) v = Bs[sc];
      }
      tile[kl][cl] = v;
    }
    __syncthreads();
    int c_loc = tid >> 3, kq = tid & 7;
    int c = ct*32 + c_loc;
    if (c < 520){
      ushort4 st;
      uint16_t* sp = (uint16_t*)&st;
      #pragma unroll
      for (int r = 0; r < 4; ++r) sp[r] = f2b(tile[kq*4 + r][c_loc]);
      uint16_t* dst = (c < 512) ? &WbsT[(size_t)c*KZ] : &Wbs2T[(size_t)(c-512)*KZ];
      *(ushort4*)&dst[kt*32 + kq*4] = st;
    }
  } else {
    // misc: hinp [B4*KH] | x0T [192*B4] | z pad init [B4*64]
    int b = bid - 2305;
    if (b < 2560){
      int idx = b*256 + tid;
      int bb = idx / KH, k = idx - bb*KH;
      float v;
      if (k < 128)      v = obs[bb*128 + k];
      else if (k < 132) v = prefs[bb*4 + (k-128)];
      else              v = (k == 132) ? 1.f : 0.f;
      hinp[idx] = f2b(v);
    } else if (b < 5632){
      int idx = (b-2560)*256 + tid;
      int c = idx >> 12;
      int bb = idx & (B4-1);
      float v = 0.f;
      if (c < 128)      v = obs[bb*128 + c];
      else if (c < 160) v = act[bb*32 + (c-128)];
      else if (c < 164) v = prefs[bb*4 + (c-160)];
      x0T[idx] = f2b(v);
    } else {
      int idx = (b-5632)*256 + tid;
      int t = idx & 63;
      int row = idx >> 6;
      uint16_t* p = (t < 32) ? z1p : zp;
      int col = 1024 + (t & 31);
      p[(size_t)row*KZ + col] = ((t & 31) == 0) ? (uint16_t)0x3F80 : (uint16_t)0;
    }
  }
}

// ---------------------------------------------------------------------------
// Generic 128x128 MFMA GEMM (used for z1).
// ---------------------------------------------------------------------------
template<int RELU, int OUTBF, int TRANS>
__global__ __launch_bounds__(256) void gemm128(
    const uint16_t* __restrict__ A, int lda,
    const uint16_t* __restrict__ BT, int ldb,
    void* __restrict__ Cv, int ldc, int K)
{
  __shared__ char smA[128*64];
  __shared__ char smB[128*64];
  int tid = threadIdx.x, w = tid >> 6, lane = tid & 63;
  int m0 = blockIdx.x*128, n0 = blockIdx.y*128;
  const uint16_t* Ab = A  + (size_t)m0*lda;
  const uint16_t* Bb = BT + (size_t)n0*ldb;
  f32x4 acc[2][8];
  #pragma unroll
  for (int mf = 0; mf < 2; ++mf)
    #pragma unroll
    for (int nf = 0; nf < 8; ++nf) acc[mf][nf] = (f32x4){0.f,0.f,0.f,0.f};
  int colg = lane & 15, hi = lane >> 4;

  for (int k0 = 0; k0 < K; k0 += 32){
    #pragma unroll
    for (int p = 0; p < 2; ++p){
      int rb = p*4 + w;
      int row = rb*16 + (lane >> 2);
      int chunk = (lane & 3) ^ ((row >> 1) & 3);
      gload16(Ab + (size_t)row*lda + k0 + chunk*8, &smA[rb*1024]);
      gload16(Bb + (size_t)row*ldb + k0 + chunk*8, &smB[rb*1024]);
    }
    __syncthreads();
    bf16x8 af[2];
    #pragma unroll
    for (int mf = 0; mf < 2; ++mf){
      int row = w*32 + mf*16 + colg;
      af[mf] = *(const bf16x8*)&smA[row*64 + ((hi ^ ((row>>1)&3)) << 4)];
    }
    #pragma unroll
    for (int nf = 0; nf < 8; ++nf){
      int row = nf*16 + colg;
      bf16x8 bfr = *(const bf16x8*)&smB[row*64 + ((hi ^ ((row>>1)&3)) << 4)];
      acc[0][nf] = __builtin_amdgcn_mfma_f32_16x16x32_bf16(af[0], bfr, acc[0][nf], 0,0,0);
      acc[1][nf] = __builtin_amdgcn_mfma_f32_16x16x32_bf16(af[1], bfr, acc[1][nf], 0,0,0);
    }
    __syncthreads();
  }
  #pragma unroll
  for (int mf = 0; mf < 2; ++mf){
    #pragma unroll
    for (int nf = 0; nf < 8; ++nf){
      int col = n0 + nf*16 + colg;
      #pragma unroll
      for (int r = 0; r < 4; ++r){
        int row = m0 + w*32 + mf*16 + hi*4 + r;
        float v = acc[mf][nf][r];
        if (RELU) v = v > 0.f ? v : 0.f;
        if (TRANS)      ((float*)Cv)[(size_t)col*ldc + row] = v;
        else if (OUTBF) ((uint16_t*)Cv)[(size_t)row*ldc + col] = f2b(v);
        else            ((float*)Cv)[(size_t)row*ldc + col] = v;
      }
    }
  }
}

// ---------------------------------------------------------------------------
// fused_zw: z-GEMM (256 blocks, dispatched first, compute-bound) overlapped
// with the big WpT0/WpT1 weight transposes (42240 blocks, BW-bound) in one
// launch — single-stream graphs can't overlap kernels, blocks co-schedule.
// ---------------------------------------------------------------------------
__global__ __launch_bounds__(256) void fused_zw(
    const uint16_t* __restrict__ z1p, const uint16_t* __restrict__ We2T,
    uint16_t* __restrict__ zp,
    const float* __restrict__ Ww0, const float* __restrict__ bw0,
    uint16_t* __restrict__ WpT0,
    const float* __restrict__ Ww1, const float* __restrict__ bw1,
    uint16_t* __restrict__ WpT1)
{
  __shared__ char sm[16384];
  int bid = blockIdx.x;
  int tid = threadIdx.x;

  if (bid < 256){
    // z = relu(z1p @ We2T^T), bf16 out stride KZ
    char* smA = sm; char* smB = sm + 8192;
    int w = tid >> 6, lane = tid & 63;
    int m0 = (bid >> 3)*128, n0 = (bid & 7)*128;
    const uint16_t* Ab = z1p  + (size_t)m0*KZ;
    const uint16_t* Bb = We2T + (size_t)n0*KZ;
    f32x4 acc[2][8];
    #pragma unroll
    for (int mf = 0; mf < 2; ++mf)
      #pragma unroll
      for (int nf = 0; nf < 8; ++nf) acc[mf][nf] = (f32x4){0.f,0.f,0.f,0.f};
    int colg = lane & 15, hi = lane >> 4;

    for (int k0 = 0; k0 < KZ; k0 += 32){
      #pragma unroll
      for (int p = 0; p < 2; ++p){
        int rb = p*4 + w;
        int row = rb*16 + (lane >> 2);
        int chunk = (lane & 3) ^ ((row >> 1) & 3);
        gload16(Ab + (size_t)row*KZ + k0 + chunk*8, &smA[rb*1024]);
        gload16(Bb + (size_t)row*KZ + k0 + chunk*8, &smB[rb*1024]);
      }
      __syncthreads();
      bf16x8 af[2];
      #pragma unroll
      for (int mf = 0; mf < 2; ++mf){
        int row = w*32 + mf*16 + colg;
        af[mf] = *(const bf16x8*)&smA[row*64 + ((hi ^ ((row>>1)&3)) << 4)];
      }
      #pragma unroll
      for (int nf = 0; nf < 8; ++nf){
        int row = nf*16 + colg;
        bf16x8 bfr = *(const bf16x8*)&smB[row*64 + ((hi ^ ((row>>1)&3)) << 4)];
        acc[0][nf] = __builtin_amdgcn_mfma_f32_16x16x32_bf16(af[0], bfr, acc[0][nf], 0,0,0);
        acc[1][nf] = __builtin_amdgcn_mfma_f32_16x16x32_bf16(af[1], bfr, acc[1][nf], 0,0,0);
      }
      __syncthreads();
    }
    #pragma unroll
    for (int mf = 0; mf < 2; ++mf){
      #pragma unroll
      for (int nf = 0; nf < 8; ++nf){
        int col = n0 + nf*16 + colg;
        #pragma unroll
        for (int r = 0; r < 4; ++r){
          int row = m0 + w*32 + mf*16 + hi*4 + r;
          float v = acc[mf][nf][r];
          v = v > 0.f ? v : 0.f;
          zp[(size_t)row*KZ + col] = f2b(v);
        }
      }
    }
  } else if (bid < 25600){
    int b = bid - 256;
    tp_tile((float(*)[33])sm, Ww0, bw0, WpT0, 24576, KZ, 1024, 20992, 192, 164,
            b % 768, b / 768);
  } else {
    int b = bid - 25600;
    tp_tile((float(*)[33])sm, Ww1, bw1, WpT1, 16384, KZ, 1024, 16384, 128, 128,
            b % 512, b / 512);
  }
}

// ---------------------------------------------------------------------------
// Combined heads GEMM: grid (32, 9). y<4 -> bsb0 (TRANS fp32); y==4 -> bsb2;
// y>=5 -> w2.
// ---------------------------------------------------------------------------
__global__ __launch_bounds__(256) void gemm_heads(
    const uint16_t* __restrict__ zp, const uint16_t* __restrict__ Wbs0T,
    const uint16_t* __restrict__ Wbs2T, const uint16_t* __restrict__ WpT2,
    float* __restrict__ bsb0, float* __restrict__ bsb2, float* __restrict__ w2)
{
  __shared__ char smA[128*64];
  __shared__ char smB[128*64];
  int y = blockIdx.y;
  const uint16_t* BT; float* Cv; int ldc, n0, trans;
  if (y < 4)      { BT = Wbs0T; Cv = bsb0; ldc = B4;  n0 = y*128;     trans = 1; }
  else if (y == 4){ BT = Wbs2T; Cv = bsb2; ldc = 128; n0 = 0;         trans = 0; }
  else            { BT = WpT2;  Cv = w2;   ldc = 512; n0 = (y-5)*128; trans = 0; }

  int tid = threadIdx.x, w = tid >> 6, lane = tid & 63;
  int m0 = blockIdx.x*128;
  const uint16_t* Ab = zp + (size_t)m0*KZ;
  const uint16_t* Bb = BT + (size_t)n0*KZ;
  f32x4 acc[2][8];
  #pragma unroll
  for (int mf = 0; mf < 2; ++mf)
    #pragma unroll
    for (int nf = 0; nf < 8; ++nf) acc[mf][nf] = (f32x4){0.f,0.f,0.f,0.f};
  int colg = lane & 15, hi = lane >> 4;

  for (int k0 = 0; k0 < KZ; k0 += 32){
    #pragma unroll
    for (int p = 0; p < 2; ++p){
      int rb = p*4 + w;
      int row = rb*16 + (lane >> 2);
      int chunk = (lane & 3) ^ ((row >> 1) & 3);
      gload16(Ab + (size_t)row*KZ + k0 + chunk*8, &smA[rb*1024]);
      gload16(Bb + (size_t)row*KZ + k0 + chunk*8, &smB[rb*1024]);
    }
    __syncthreads();
    bf16x8 af[2];
    #pragma unroll
    for (int mf = 0; mf < 2; ++mf){
      int row = w*32 + mf*16 + colg;
      af[mf] = *(const bf16x8*)&smA[row*64 + ((hi ^ ((row>>1)&3)) << 4)];
    }
    #pragma unroll
    for (int nf = 0; nf < 8; ++nf){
      int row = nf*16 + colg;
      bf16x8 bfr = *(const bf16x8*)&smB[row*64 + ((hi ^ ((row>>1)&3)) << 4)];
      acc[0][nf] = __builtin_amdgcn_mfma_f32_16x16x32_bf16(af[0], bfr, acc[0][nf], 0,0,0);
      acc[1][nf] = __builtin_amdgcn_mfma_f32_16x16x32_bf16(af[1], bfr, acc[1][nf], 0,0,0);
    }
    __syncthreads();
  }
  #pragma unroll
  for (int mf = 0; mf < 2; ++mf){
    #pragma unroll
    for (int nf = 0; nf < 8; ++nf){
      int col = n0 + nf*16 + colg;
      #pragma unroll
      for (int r = 0; r < 4; ++r){
        int row = m0 + w*32 + mf*16 + hi*4 + r;
        float v = acc[mf][nf][r];
        if (trans) Cv[(size_t)col*ldc + row] = v;
        else       Cv[(size_t)row*ldc + col] = v;
      }
    }
  }
}

// ---------------------------------------------------------------------------
// Fused hypernet layer (verified r9/r12 structure — DO NOT hoist addressing
// out of the lambdas: r11's precomputed pointers spilled past the register
// wall, 226->468us). Block = 256 samples x 2 neurons, 8 waves 2M x 4N
// (wave tile 128 x DINP/2), 3 LDS buffers, counted vmcnt, 1 barrier/half,
// compute compiler-scheduled.
// ---------------------------------------------------------------------------
template<int DINP>
__global__ __launch_bounds__(512, 2) void hyper2n(
    const uint16_t* __restrict__ zp,     // [B4, KZ]
    const uint16_t* __restrict__ WpT,    // [128*DINP, KZ] grouped by neuron
    const uint16_t* __restrict__ xT,     // [DINP, B4]
    const float*  __restrict__ bsbT,     // [256, B4]: row o=bias, 128+o=scale
    uint16_t* __restrict__ outT,         // [128, B4]
    int relu)
{
  constexpr int NF     = DINP/32;        // frags per wave per k-half (6 / 4)
  constexpr int BCALLS = DINP/64;        // B stage calls per half (3 / 2)
  constexpr int WAITN  = 2 + BCALLS;     // counted vmcnt at half boundary
  constexpr int HBUF   = 16384 + 2*DINP*64;  // A 16KB + B 2*DINP rows x 64B
  constexpr int NH     = KZ/32;          // 33 half-tiles
  __shared__ char sm[3*HBUF];

  int tid = threadIdx.x, w = tid >> 6, lane = tid & 63;
  int wm = w >> 2, wn = w & 3;           // 2M x 4N
  int f = blockIdx.x;
  int xcd = f & 7;
  int j = f >> 3;               // 0..127
  int pair = j >> 1;            // 0..63
  int mt = xcd*2 + (j & 1);     // 0..15
  int m0 = mt*256;
  const uint16_t* Ag = zp  + (size_t)m0*KZ;
  const uint16_t* Bg = WpT + (size_t)pair*(2*DINP)*KZ;
  int colg = lane & 15, hi = lane >> 4;

  f32x4 acc[8][NF];
  #pragma unroll
  for (int mf = 0; mf < 8; ++mf)
    #pragma unroll
    for (int nf = 0; nf < NF; ++nf) acc[mf][nf] = (f32x4){0.f,0.f,0.f,0.f};

  auto SA = [&](int h, int a){
    int row = a*128 + (tid >> 2);
    int ch  = (tid & 3) ^ ((row >> 1) & 3);
    gload16(Ag + (size_t)row*KZ + h*32 + ch*8,
            sm + (h%3)*HBUF + a*8192 + w*1024);
  };
  auto SB = [&](int h, int b){
    int row = b*128 + (tid >> 2);
    int ch  = (tid & 3) ^ ((row >> 1) & 3);
    gload16(Bg + (size_t)row*KZ + h*32 + ch*8,
            sm + (h%3)*HBUF + 16384 + b*8192 + w*1024);
  };

  SA(0,0); SA(0,1);
  #pragma unroll
  for (int b = 0; b < BCALLS; ++b) SB(0,b);
  SA(1,0); SA(1,1);
  #pragma unroll
  for (int b = 0; b < BCALLS; ++b) SB(1,b);

  for (int h = 0; h < NH; ++h){
    const char* base = sm + (h%3)*HBUF;
    if (h == NH-1) asm volatile("s_waitcnt vmcnt(0)" ::: "memory");
    else           asm volatile("s_waitcnt vmcnt(%0)" :: "i"(WAITN) : "memory");
    __builtin_amdgcn_s_barrier();
    if (h + 2 < NH){
      SA(h+2,0); SA(h+2,1);
      #pragma unroll
      for (int b = 0; b < BCALLS; ++b) SB(h+2,b);
    }
    bf16x8 Bf[NF];
    #pragma unroll
    for (int nf = 0; nf < NF; ++nf){
      int rc = wn*(DINP/2) + nf*16 + colg;
      Bf[nf] = *(const bf16x8*)(base + 16384 + rc*64 + ((hi ^ ((rc>>1)&3)) << 4));
    }
    #pragma unroll
    for (int m = 0; m < 8; ++m){
      int row = wm*128 + m*16 + colg;
      bf16x8 a = *(const bf16x8*)(base + row*64 + ((hi ^ ((row>>1)&3)) << 4));
      #pragma unroll
      for (int nf = 0; nf < NF; ++nf)
        acc[m][nf] = __builtin_amdgcn_mfma_f32_16x16x32_bf16(a, Bf[nf], acc[m][nf], 0,0,0);
    }
  }

  // ---- epilogue: per-mf contract + reduce + LDS combine ----
  __syncthreads();
  float* red = (float*)sm;    // [2 parity][2 o_loc][256]
  int parity = wn & 1, o_loc = wn >> 1;
  #pragma unroll
  for (int mf = 0; mf < 8; ++mf){
    float p0=0.f, p1=0.f, p2=0.f, p3=0.f;
    int b0 = m0 + wm*128 + mf*16 + hi*4;
    #pragma unroll
    for (int nf = 0; nf < NF; ++nf){
      int il = parity*(DINP/2) + nf*16 + colg;
      ushort4 xv = *(const ushort4*)(xT + (size_t)il*B4 + b0);
      f32x4 a = acc[mf][nf];
      p0 += a[0]*b2f(xv.x); p1 += a[1]*b2f(xv.y);
      p2 += a[2]*b2f(xv.z); p3 += a[3]*b2f(xv.w);
    }
    #pragma unroll
    for (int off = 1; off < 16; off <<= 1){
      p0 += __shfl_xor(p0, off); p1 += __shfl_xor(p1, off);
      p2 += __shfl_xor(p2, off); p3 += __shfl_xor(p3, off);
    }
    if (colg == 0){
      int rloc = wm*128 + mf*16 + hi*4;
      float* rp = red + parity*512 + o_loc*256 + rloc;
      rp[0] = p0; rp[1] = p1; rp[2] = p2; rp[3] = p3;
    }
  }
  __syncthreads();
  {
    int o_l = tid >> 8, row = tid & 255;
    int o = pair*2 + o_l;
    float v = red[o_l*256 + row] + red[512 + o_l*256 + row];
    float bv = bsbT[(size_t)o*B4 + m0 + row];
    float sv = bsbT[(size_t)(128+o)*B4 + m0 + row];
    float val = (v + bv) * sv;
    if (relu) val = val > 0.f ? val : 0.f;
    outT[(size_t)o*B4 + m0 + row] = f2b(val);
  }
}

// final layer: out[b,o] = (sum_i w2[b,o*128+i]*x2[i,b] + b2[b,o]) * s2[b,o]
__global__ __launch_bounds__(256) void finalize_k(
    const float* __restrict__ w2, const uint16_t* __restrict__ x2T,
    const float* __restrict__ bs2, float* __restrict__ out)
{
  int tid = threadIdx.x;
  int o = tid & 3;
  int b = blockIdx.x*64 + (tid >> 2);
  const float* wr = w2 + (size_t)b*512 + o*128;
  float dot = 0.f;
  #pragma unroll
  for (int i = 0; i < 128; i += 4){
    float4 wv = *(const float4*)(wr + i);
    dot += wv.x * b2f(x2T[(size_t)(i+0)*B4 + b]);
    dot += wv.y * b2f(x2T[(size_t)(i+1)*B4 + b]);
    dot += wv.z * b2f(x2T[(size_t)(i+2)*B4 + b]);
    dot += wv.w * b2f(x2T[(size_t)(i+3)*B4 + b]);
  }
  float bv = bs2[(size_t)b*128 + o];
  float sv = bs2[(size_t)b*128 + 4 + o];
  out[b*4 + o] = (dot + bv) * sv;
}

// ---------------------------------------------------------------------------
extern "C" void kernel_launch(void* const* d_in, const int* in_sizes, int n_in,
                              void* d_out, int out_size, void* d_ws, size_t ws_size,
                              hipStream_t stream)
{
  const float* obs   = (const float*)d_in[0];
  const float* act   = (const float*)d_in[1];
  const float* prefs = (const float*)d_in[2];
  const float* We1 = (const float*)d_in[3];
  const float* be1 = (const float*)d_in[4];
  const float* We2 = (const float*)d_in[5];
  const float* be2 = (const float*)d_in[6];
  const float* Ww0 = (const float*)d_in[7],  *bw0 = (const float*)d_in[8];
  const float* Wb0 = (const float*)d_in[9],  *bb0 = (const float*)d_in[10];
  const float* Ws0 = (const float*)d_in[11], *bs0i = (const float*)d_in[12];
  const float* Ww1 = (const float*)d_in[13], *bw1 = (const float*)d_in[14];
  const float* Wb1 = (const float*)d_in[15], *bb1 = (const float*)d_in[16];
  const float* Ws1 = (const float*)d_in[17], *bs1i = (const float*)d_in[18];
  const float* Ww2 = (const float*)d_in[19], *bw2 = (const float*)d_in[20];
  const float* Wb2 = (const float*)d_in[21], *bb2 = (const float*)d_in[22];
  const float* Ws2 = (const float*)d_in[23], *bs2i = (const float*)d_in[24];

  char* ws = (char*)d_ws;
  size_t off = 0;
  auto alloc = [&](size_t bytes)->char*{
    char* p = ws + off; off += (bytes + 255) & ~(size_t)255; return p;
  };
  uint16_t* WpT0  = (uint16_t*)alloc((size_t)24576*KZ*2);  // 128 * 192 rows
  uint16_t* WpT1  = (uint16_t*)alloc((size_t)16384*KZ*2);
  uint16_t* WpT2  = (uint16_t*)alloc((size_t)512*KZ*2);
  uint16_t* We1T  = (uint16_t*)alloc((size_t)1024*KH*2);
  uint16_t* We2T  = (uint16_t*)alloc((size_t)1024*KZ*2);
  uint16_t* Wbs0T = (uint16_t*)alloc((size_t)256*KZ*2);    // contiguous with
  uint16_t* Wbs1T = (uint16_t*)alloc((size_t)256*KZ*2);    // Wbs0T (512 rows)
  uint16_t* Wbs2T = (uint16_t*)alloc((size_t)128*KZ*2);
  uint16_t* hinp  = (uint16_t*)alloc((size_t)B4*KH*2);
  uint16_t* z1p   = (uint16_t*)alloc((size_t)B4*KZ*2);
  uint16_t* zp    = (uint16_t*)alloc((size_t)B4*KZ*2);
  float*    bsb0  = (float*)alloc((size_t)256*B4*4);   // transposed [256][B4]
  float*    bsb1  = (float*)alloc((size_t)256*B4*4);   // contiguous with bsb0
  float*    bsb2  = (float*)alloc((size_t)B4*128*4);
  uint16_t* x0T   = (uint16_t*)alloc((size_t)192*B4*2);
  uint16_t* x1T   = (uint16_t*)alloc((size_t)128*B4*2);
  uint16_t* x2T   = (uint16_t*)alloc((size_t)128*B4*2);
  float*    w2    = (float*)alloc((size_t)B4*512*4);
  (void)ws_size; (void)in_sizes; (void)n_in; (void)out_size;
  (void)Wbs1T;

  hipMemsetAsync(Wbs2T, 0, (size_t)128*KZ*2, stream);

  dim3 blk(256);
  // small prep: everything z1/heads need (8961 blocks)
  prep_small<<<dim3(8961),blk,0,stream>>>(
      We1, be1, We2, be2, Ww2, bw2,
      Wb0, bb0, Ws0, bs0i, Wb1, bb1, Ws1, bs1i, Wb2, bb2, Ws2, bs2i,
      obs, act, prefs,
      We1T, We2T, WpT2, Wbs0T, Wbs2T,
      hinp, x0T, z1p, zp);

  // z1 = relu(hin' @ We1')   [B,1024] bf16 into z1p (stride KZ)
  gemm128<1,1,0><<<dim3(32,8),blk,0,stream>>>(hinp, KH, We1T, KH, z1p, KZ, KH);

  // z-GEMM overlapped with the big WpT0/WpT1 transposes (42496 blocks)
  fused_zw<<<dim3(42496),blk,0,stream>>>(z1p, We2T, zp,
                                         Ww0, bw0, WpT0, Ww1, bw1, WpT1);

  // all head GEMMs (bsb0 TRANS, bsb2, w2) in one launch
  gemm_heads<<<dim3(32,9),blk,0,stream>>>(zp, Wbs0T, Wbs2T, WpT2, bsb0, bsb2, w2);

  // fused hyper layers 0 and 1: 1024 blocks (8 xcd * 64 pairs * 2 m-tiles)
  hyper2n<192><<<dim3(1024),dim3(512),0,stream>>>(zp, WpT0, x0T, bsb0, x1T, 1);
  hyper2n<128><<<dim3(1024),dim3(512),0,stream>>>(zp, WpT1, x1T, bsb1, x2T, 1);

  finalize_k<<<dim3(B4/64),blk,0,stream>>>(w2, x2T, bsb2, (float*)d_out);
}

// Round 15
// 505.792 us; speedup vs baseline: 1.1049x; 1.1049x over previous
//
#include <hip/hip_runtime.h>
#include <hip/hip_bf16.h>
#include <stdint.h>

#define B4 4096
#define KZ 1056   // padded z width: 1024 + 1 (ones col) + 31 pad (33 x 32)
#define KH 160    // padded hypernet-input width: 132 + 1 + pad

typedef short bf16x8 __attribute__((ext_vector_type(8)));
typedef float f32x4 __attribute__((ext_vector_type(4)));

__device__ __forceinline__ float b2f(uint16_t u){
  union {float f; uint32_t i;} v; v.i = ((uint32_t)u)<<16; return v.f;
}
__device__ __forceinline__ uint16_t f2b(float f){
  union {float fv; uint32_t i;} v; v.fv = f;
  uint32_t r = v.i + 0x7FFFu + ((v.i>>16)&1u);
  return (uint16_t)(r>>16);
}
__device__ __forceinline__ void gload16(const void* g, void* l){
  __builtin_amdgcn_global_load_lds(
      (__attribute__((address_space(1))) void*)(g),
      (__attribute__((address_space(3))) void*)(l), 16, 0, 0);
}

// ---------------------------------------------------------------------------
// Transpose tile body (shared by all weight transposes in the mega kernel).
// dst[c][k] (bf16, K-contiguous) from src fp32 [Ksrc][src_ld]; row k==Ksrc
// gets bias; k>Ksrc zero; din_dst/din_src handles column zero-padding.
// ---------------------------------------------------------------------------
__device__ __forceinline__ void tp_tile(
    float (*tile)[33],
    const float* __restrict__ src, const float* __restrict__ bias,
    uint16_t* __restrict__ dst,
    int Ncols, int Kdst, int Ksrc, int src_ld, int din_dst, int din_src,
    int ct, int kt)
{
  int tid = threadIdx.x;
  int cl = tid & 31, kg = tid >> 5;
  #pragma unroll
  for (int r = 0; r < 4; ++r){
    int kl = kg*4 + r;
    int k  = kt*32 + kl;
    int c  = ct*32 + cl;
    float v = 0.f;
    if (c < Ncols){
      int o = c / din_dst, i = c - o*din_dst;
      if (i < din_src){
        int sc = o*din_src + i;
        if (k < Ksrc)       v = src[(size_t)k*src_ld + sc];
        else if (k == Ksrc) v = bias[sc];
      }
    }
    tile[kl][cl] = v;
  }
  __syncthreads();
  int c_loc = tid >> 3, kq = tid & 7;
  int c = ct*32 + c_loc;
  if (c < Ncols){
    ushort4 st;
    uint16_t* sp = (uint16_t*)&st;
    #pragma unroll
    for (int r = 0; r < 4; ++r) sp[r] = f2b(tile[kq*4 + r][c_loc]);
    *(ushort4*)&dst[(size_t)c*Kdst + kt*32 + kq*4] = st;
  }
}

// ---------------------------------------------------------------------------
// Mega prep kernel: ALL weight transposes + bias/scale transpose + input
// packing + z pad init in ONE launch (range decode on flat blockIdx).
// Ranges: WpT0 25344 | WpT1 16896 | WpT2 528 | We1T 160 | We2T 1056 |
//         bs 561 | pack_misc 6656  => grid 51201.
// NOTE (r14 lesson): do NOT co-schedule a GEMM inside this kernel — the
// BW-bound transpose blocks starve the GEMM's staging path and the kernel
// retires at the stretched GEMM's pace (+52us).
// ---------------------------------------------------------------------------
__global__ __launch_bounds__(256) void mega_prep(
    const float* __restrict__ Ww0, const float* __restrict__ bw0,
    const float* __restrict__ Ww1, const float* __restrict__ bw1,
    const float* __restrict__ Ww2, const float* __restrict__ bw2,
    const float* __restrict__ We1, const float* __restrict__ be1,
    const float* __restrict__ We2, const float* __restrict__ be2,
    const float* __restrict__ Wb0, const float* __restrict__ bb0,
    const float* __restrict__ Ws0, const float* __restrict__ bs0,
    const float* __restrict__ Wb1, const float* __restrict__ bb1,
    const float* __restrict__ Ws1, const float* __restrict__ bs1,
    const float* __restrict__ Wb2, const float* __restrict__ bb2,
    const float* __restrict__ Ws2, const float* __restrict__ bs2,
    const float* __restrict__ obs, const float* __restrict__ act,
    const float* __restrict__ prefs,
    uint16_t* __restrict__ WpT0, uint16_t* __restrict__ WpT1,
    uint16_t* __restrict__ WpT2, uint16_t* __restrict__ We1T,
    uint16_t* __restrict__ We2T, uint16_t* __restrict__ WbsT,
    uint16_t* __restrict__ Wbs2T,
    uint16_t* __restrict__ hinp, uint16_t* __restrict__ x0T,
    uint16_t* __restrict__ z1p, uint16_t* __restrict__ zp)
{
  __shared__ float tile[32][33];
  int bid = blockIdx.x;
  int tid = threadIdx.x;

  if (bid < 25344){
    tp_tile(tile, Ww0, bw0, WpT0, 24576, KZ, 1024, 20992, 192, 164,
            bid % 768, bid / 768);
  } else if (bid < 42240){
    int b = bid - 25344;
    tp_tile(tile, Ww1, bw1, WpT1, 16384, KZ, 1024, 16384, 128, 128,
            b % 512, b / 512);
  } else if (bid < 42768){
    int b = bid - 42240;
    tp_tile(tile, Ww2, bw2, WpT2, 512, KZ, 1024, 512, 128, 128,
            b % 16, b / 16);
  } else if (bid < 42928){
    int b = bid - 42768;
    tp_tile(tile, We1, be1, We1T, 1024, KH, 132, 1024, 1024, 1024,
            b % 32, b / 32);
  } else if (bid < 43984){
    int b = bid - 42928;
    tp_tile(tile, We2, be2, We2T, 1024, KZ, 1024, 1024, 1024, 1024,
            b % 32, b / 32);
  } else if (bid < 44545){
    // fused bias/scale head transpose: WbsT 512 cols (Wb0|Ws0|Wb1|Ws1),
    // Wbs2T 8 cols (Wb2|Ws2)
    int b = bid - 43984;
    int ct = b % 17, kt = b / 17;
    int cl = tid & 31, kg = tid >> 5;
    #pragma unroll
    for (int r = 0; r < 4; ++r){
      int kl = kg*4 + r;
      int k  = kt*32 + kl;
      int c  = ct*32 + cl;
      float v = 0.f;
      if (c < 512){
        int sel = c >> 7, sc = c & 127;
        const float* S  = (sel==0) ? Wb0 : (sel==1) ? Ws0 : (sel==2) ? Wb1 : Ws1;
        const float* Bs = (sel==0) ? bb0 : (sel==1) ? bs0 : (sel==2) ? bb1 : bs1;
        if (k < 1024)       v = S[(size_t)k*128 + sc];
        else if (k == 1024) v = Bs[sc];
      } else if (c < 520){
        int cc = c - 512;
        int sel = cc >> 2, sc = cc & 3;
        const float* S  = sel ? Ws2 : Wb2;
        const float* Bs = sel ? bs2 : bb2;
        if (k < 1024)       v = S[(size_t)k*4 + sc];
        else if (k == 1024) v = Bs[sc];
      }
      tile[kl][cl] = v;
    }
    __syncthreads();
    int c_loc = tid >> 3, kq = tid & 7;
    int c = ct*32 + c_loc;
    if (c < 520){
      ushort4 st;
      uint16_t* sp = (uint16_t*)&st;
      #pragma unroll
      for (int r = 0; r < 4; ++r) sp[r] = f2b(tile[kq*4 + r][c_loc]);
      uint16_t* dst = (c < 512) ? &WbsT[(size_t)c*KZ] : &Wbs2T[(size_t)(c-512)*KZ];
      *(ushort4*)&dst[kt*32 + kq*4] = st;
    }
  } else {
    // pack_misc: hinp [B4*KH] | x0T [192*B4] | z pad init [B4*64]
    int b = bid - 44545;
    if (b < 2560){
      int idx = b*256 + tid;
      int bb = idx / KH, k = idx - bb*KH;
      float v;
      if (k < 128)      v = obs[bb*128 + k];
      else if (k < 132) v = prefs[bb*4 + (k-128)];
      else              v = (k == 132) ? 1.f : 0.f;
      hinp[idx] = f2b(v);
    } else if (b < 5632){
      int idx = (b-2560)*256 + tid;
      int c = idx >> 12;
      int bb = idx & (B4-1);
      float v = 0.f;
      if (c < 128)      v = obs[bb*128 + c];
      else if (c < 160) v = act[bb*32 + (c-128)];
      else if (c < 164) v = prefs[bb*4 + (c-160)];
      x0T[idx] = f2b(v);
    } else {
      int idx = (b-5632)*256 + tid;
      int t = idx & 63;
      int row = idx >> 6;
      uint16_t* p = (t < 32) ? z1p : zp;
      int col = 1024 + (t & 31);
      p[(size_t)row*KZ + col] = ((t & 31) == 0) ? (uint16_t)0x3F80 : (uint16_t)0;
    }
  }
}

// ---------------------------------------------------------------------------
// Generic 128x128 MFMA GEMM (templated; used for z1 / z).
// ---------------------------------------------------------------------------
template<int RELU, int OUTBF, int TRANS>
__global__ __launch_bounds__(256) void gemm128(
    const uint16_t* __restrict__ A, int lda,
    const uint16_t* __restrict__ BT, int ldb,
    void* __restrict__ Cv, int ldc, int K)
{
  __shared__ char smA[128*64];
  __shared__ char smB[128*64];
  int tid = threadIdx.x, w = tid >> 6, lane = tid & 63;
  int m0 = blockIdx.x*128, n0 = blockIdx.y*128;
  const uint16_t* Ab = A  + (size_t)m0*lda;
  const uint16_t* Bb = BT + (size_t)n0*ldb;
  f32x4 acc[2][8];
  #pragma unroll
  for (int mf = 0; mf < 2; ++mf)
    #pragma unroll
    for (int nf = 0; nf < 8; ++nf) acc[mf][nf] = (f32x4){0.f,0.f,0.f,0.f};
  int colg = lane & 15, hi = lane >> 4;

  for (int k0 = 0; k0 < K; k0 += 32){
    #pragma unroll
    for (int p = 0; p < 2; ++p){
      int rb = p*4 + w;
      int row = rb*16 + (lane >> 2);
      int chunk = (lane & 3) ^ ((row >> 1) & 3);
      gload16(Ab + (size_t)row*lda + k0 + chunk*8, &smA[rb*1024]);
      gload16(Bb + (size_t)row*ldb + k0 + chunk*8, &smB[rb*1024]);
    }
    __syncthreads();
    bf16x8 af[2];
    #pragma unroll
    for (int mf = 0; mf < 2; ++mf){
      int row = w*32 + mf*16 + colg;
      af[mf] = *(const bf16x8*)&smA[row*64 + ((hi ^ ((row>>1)&3)) << 4)];
    }
    #pragma unroll
    for (int nf = 0; nf < 8; ++nf){
      int row = nf*16 + colg;
      bf16x8 bfr = *(const bf16x8*)&smB[row*64 + ((hi ^ ((row>>1)&3)) << 4)];
      acc[0][nf] = __builtin_amdgcn_mfma_f32_16x16x32_bf16(af[0], bfr, acc[0][nf], 0,0,0);
      acc[1][nf] = __builtin_amdgcn_mfma_f32_16x16x32_bf16(af[1], bfr, acc[1][nf], 0,0,0);
    }
    __syncthreads();
  }
  #pragma unroll
  for (int mf = 0; mf < 2; ++mf){
    #pragma unroll
    for (int nf = 0; nf < 8; ++nf){
      int col = n0 + nf*16 + colg;
      #pragma unroll
      for (int r = 0; r < 4; ++r){
        int row = m0 + w*32 + mf*16 + hi*4 + r;
        float v = acc[mf][nf][r];
        if (RELU) v = v > 0.f ? v : 0.f;
        if (TRANS)      ((float*)Cv)[(size_t)col*ldc + row] = v;
        else if (OUTBF) ((uint16_t*)Cv)[(size_t)row*ldc + col] = f2b(v);
        else            ((float*)Cv)[(size_t)row*ldc + col] = v;
      }
    }
  }
}

// ---------------------------------------------------------------------------
// Combined heads GEMM: grid (32, 9). y<4 -> bsb0 (TRANS fp32, 512 cols of
// Wbs0T); y==4 -> bsb2 (plain fp32, Wbs2T, ldc=128); y>=5 -> w2 (plain fp32,
// WpT2, ldc=512). One launch instead of three.
// ---------------------------------------------------------------------------
__global__ __launch_bounds__(256) void gemm_heads(
    const uint16_t* __restrict__ zp, const uint16_t* __restrict__ Wbs0T,
    const uint16_t* __restrict__ Wbs2T, const uint16_t* __restrict__ WpT2,
    float* __restrict__ bsb0, float* __restrict__ bsb2, float* __restrict__ w2)
{
  __shared__ char smA[128*64];
  __shared__ char smB[128*64];
  int y = blockIdx.y;
  const uint16_t* BT; float* Cv; int ldc, n0, trans;
  if (y < 4)      { BT = Wbs0T; Cv = bsb0; ldc = B4;  n0 = y*128;     trans = 1; }
  else if (y == 4){ BT = Wbs2T; Cv = bsb2; ldc = 128; n0 = 0;         trans = 0; }
  else            { BT = WpT2;  Cv = w2;   ldc = 512; n0 = (y-5)*128; trans = 0; }

  int tid = threadIdx.x, w = tid >> 6, lane = tid & 63;
  int m0 = blockIdx.x*128;
  const uint16_t* Ab = zp + (size_t)m0*KZ;
  const uint16_t* Bb = BT + (size_t)n0*KZ;
  f32x4 acc[2][8];
  #pragma unroll
  for (int mf = 0; mf < 2; ++mf)
    #pragma unroll
    for (int nf = 0; nf < 8; ++nf) acc[mf][nf] = (f32x4){0.f,0.f,0.f,0.f};
  int colg = lane & 15, hi = lane >> 4;

  for (int k0 = 0; k0 < KZ; k0 += 32){
    #pragma unroll
    for (int p = 0; p < 2; ++p){
      int rb = p*4 + w;
      int row = rb*16 + (lane >> 2);
      int chunk = (lane & 3) ^ ((row >> 1) & 3);
      gload16(Ab + (size_t)row*KZ + k0 + chunk*8, &smA[rb*1024]);
      gload16(Bb + (size_t)row*KZ + k0 + chunk*8, &smB[rb*1024]);
    }
    __syncthreads();
    bf16x8 af[2];
    #pragma unroll
    for (int mf = 0; mf < 2; ++mf){
      int row = w*32 + mf*16 + colg;
      af[mf] = *(const bf16x8*)&smA[row*64 + ((hi ^ ((row>>1)&3)) << 4)];
    }
    #pragma unroll
    for (int nf = 0; nf < 8; ++nf){
      int row = nf*16 + colg;
      bf16x8 bfr = *(const bf16x8*)&smB[row*64 + ((hi ^ ((row>>1)&3)) << 4)];
      acc[0][nf] = __builtin_amdgcn_mfma_f32_16x16x32_bf16(af[0], bfr, acc[0][nf], 0,0,0);
      acc[1][nf] = __builtin_amdgcn_mfma_f32_16x16x32_bf16(af[1], bfr, acc[1][nf], 0,0,0);
    }
    __syncthreads();
  }
  #pragma unroll
  for (int mf = 0; mf < 2; ++mf){
    #pragma unroll
    for (int nf = 0; nf < 8; ++nf){
      int col = n0 + nf*16 + colg;
      #pragma unroll
      for (int r = 0; r < 4; ++r){
        int row = m0 + w*32 + mf*16 + hi*4 + r;
        float v = acc[mf][nf][r];
        if (trans) Cv[(size_t)col*ldc + row] = v;
        else       Cv[(size_t)row*ldc + col] = v;
      }
    }
  }
}

// ---------------------------------------------------------------------------
// Fused hypernet layer (verified r9/r12 structure — DO NOT hoist addressing
// out of the lambdas: r11's precomputed pointers spilled past the register
// wall, 226->468us). Block = 256 samples x 2 neurons, 8 waves 2M x 4N
// (wave tile 128 x DINP/2), 3 LDS buffers, counted vmcnt, 1 barrier/half,
// compute compiler-scheduled.
// ---------------------------------------------------------------------------
template<int DINP>
__global__ __launch_bounds__(512, 2) void hyper2n(
    const uint16_t* __restrict__ zp,     // [B4, KZ]
    const uint16_t* __restrict__ WpT,    // [128*DINP, KZ] grouped by neuron
    const uint16_t* __restrict__ xT,     // [DINP, B4]
    const float*  __restrict__ bsbT,     // [256, B4]: row o=bias, 128+o=scale
    uint16_t* __restrict__ outT,         // [128, B4]
    int relu)
{
  constexpr int NF     = DINP/32;        // frags per wave per k-half (6 / 4)
  constexpr int BCALLS = DINP/64;        // B stage calls per half (3 / 2)
  constexpr int WAITN  = 2 + BCALLS;     // counted vmcnt at half boundary
  constexpr int HBUF   = 16384 + 2*DINP*64;  // A 16KB + B 2*DINP rows x 64B
  constexpr int NH     = KZ/32;          // 33 half-tiles
  __shared__ char sm[3*HBUF];

  int tid = threadIdx.x, w = tid >> 6, lane = tid & 63;
  int wm = w >> 2, wn = w & 3;           // 2M x 4N
  int f = blockIdx.x;
  int xcd = f & 7;
  int j = f >> 3;               // 0..127
  int pair = j >> 1;            // 0..63
  int mt = xcd*2 + (j & 1);     // 0..15
  int m0 = mt*256;
  const uint16_t* Ag = zp  + (size_t)m0*KZ;
  const uint16_t* Bg = WpT + (size_t)pair*(2*DINP)*KZ;
  int colg = lane & 15, hi = lane >> 4;

  f32x4 acc[8][NF];
  #pragma unroll
  for (int mf = 0; mf < 8; ++mf)
    #pragma unroll
    for (int nf = 0; nf < NF; ++nf) acc[mf][nf] = (f32x4){0.f,0.f,0.f,0.f};

  auto SA = [&](int h, int a){
    int row = a*128 + (tid >> 2);
    int ch  = (tid & 3) ^ ((row >> 1) & 3);
    gload16(Ag + (size_t)row*KZ + h*32 + ch*8,
            sm + (h%3)*HBUF + a*8192 + w*1024);
  };
  auto SB = [&](int h, int b){
    int row = b*128 + (tid >> 2);
    int ch  = (tid & 3) ^ ((row >> 1) & 3);
    gload16(Bg + (size_t)row*KZ + h*32 + ch*8,
            sm + (h%3)*HBUF + 16384 + b*8192 + w*1024);
  };

  SA(0,0); SA(0,1);
  #pragma unroll
  for (int b = 0; b < BCALLS; ++b) SB(0,b);
  SA(1,0); SA(1,1);
  #pragma unroll
  for (int b = 0; b < BCALLS; ++b) SB(1,b);

  for (int h = 0; h < NH; ++h){
    const char* base = sm + (h%3)*HBUF;
    if (h == NH-1) asm volatile("s_waitcnt vmcnt(0)" ::: "memory");
    else           asm volatile("s_waitcnt vmcnt(%0)" :: "i"(WAITN) : "memory");
    __builtin_amdgcn_s_barrier();
    if (h + 2 < NH){
      SA(h+2,0); SA(h+2,1);
      #pragma unroll
      for (int b = 0; b < BCALLS; ++b) SB(h+2,b);
    }
    bf16x8 Bf[NF];
    #pragma unroll
    for (int nf = 0; nf < NF; ++nf){
      int rc = wn*(DINP/2) + nf*16 + colg;
      Bf[nf] = *(const bf16x8*)(base + 16384 + rc*64 + ((hi ^ ((rc>>1)&3)) << 4));
    }
    #pragma unroll
    for (int m = 0; m < 8; ++m){
      int row = wm*128 + m*16 + colg;
      bf16x8 a = *(const bf16x8*)(base + row*64 + ((hi ^ ((row>>1)&3)) << 4));
      #pragma unroll
      for (int nf = 0; nf < NF; ++nf)
        acc[m][nf] = __builtin_amdgcn_mfma_f32_16x16x32_bf16(a, Bf[nf], acc[m][nf], 0,0,0);
    }
  }

  // ---- epilogue: per-mf contract + reduce + LDS combine ----
  __syncthreads();
  float* red = (float*)sm;    // [2 parity][2 o_loc][256]
  int parity = wn & 1, o_loc = wn >> 1;
  #pragma unroll
  for (int mf = 0; mf < 8; ++mf){
    float p0=0.f, p1=0.f, p2=0.f, p3=0.f;
    int b0 = m0 + wm*128 + mf*16 + hi*4;
    #pragma unroll
    for (int nf = 0; nf < NF; ++nf){
      int il = parity*(DINP/2) + nf*16 + colg;
      ushort4 xv = *(const ushort4*)(xT + (size_t)il*B4 + b0);
      f32x4 a = acc[mf][nf];
      p0 += a[0]*b2f(xv.x); p1 += a[1]*b2f(xv.y);
      p2 += a[2]*b2f(xv.z); p3 += a[3]*b2f(xv.w);
    }
    #pragma unroll
    for (int off = 1; off < 16; off <<= 1){
      p0 += __shfl_xor(p0, off); p1 += __shfl_xor(p1, off);
      p2 += __shfl_xor(p2, off); p3 += __shfl_xor(p3, off);
    }
    if (colg == 0){
      int rloc = wm*128 + mf*16 + hi*4;
      float* rp = red + parity*512 + o_loc*256 + rloc;
      rp[0] = p0; rp[1] = p1; rp[2] = p2; rp[3] = p3;
    }
  }
  __syncthreads();
  {
    int o_l = tid >> 8, row = tid & 255;
    int o = pair*2 + o_l;
    float v = red[o_l*256 + row] + red[512 + o_l*256 + row];
    float bv = bsbT[(size_t)o*B4 + m0 + row];
    float sv = bsbT[(size_t)(128+o)*B4 + m0 + row];
    float val = (v + bv) * sv;
    if (relu) val = val > 0.f ? val : 0.f;
    outT[(size_t)o*B4 + m0 + row] = f2b(val);
  }
}

// final layer: out[b,o] = (sum_i w2[b,o*128+i]*x2[i,b] + b2[b,o]) * s2[b,o]
__global__ __launch_bounds__(256) void finalize_k(
    const float* __restrict__ w2, const uint16_t* __restrict__ x2T,
    const float* __restrict__ bs2, float* __restrict__ out)
{
  int tid = threadIdx.x;
  int o = tid & 3;
  int b = blockIdx.x*64 + (tid >> 2);
  const float* wr = w2 + (size_t)b*512 + o*128;
  float dot = 0.f;
  #pragma unroll
  for (int i = 0; i < 128; i += 4){
    float4 wv = *(const float4*)(wr + i);
    dot += wv.x * b2f(x2T[(size_t)(i+0)*B4 + b]);
    dot += wv.y * b2f(x2T[(size_t)(i+1)*B4 + b]);
    dot += wv.z * b2f(x2T[(size_t)(i+2)*B4 + b]);
    dot += wv.w * b2f(x2T[(size_t)(i+3)*B4 + b]);
  }
  float bv = bs2[(size_t)b*128 + o];
  float sv = bs2[(size_t)b*128 + 4 + o];
  out[b*4 + o] = (dot + bv) * sv;
}

// ---------------------------------------------------------------------------
extern "C" void kernel_launch(void* const* d_in, const int* in_sizes, int n_in,
                              void* d_out, int out_size, void* d_ws, size_t ws_size,
                              hipStream_t stream)
{
  const float* obs   = (const float*)d_in[0];
  const float* act   = (const float*)d_in[1];
  const float* prefs = (const float*)d_in[2];
  const float* We1 = (const float*)d_in[3];
  const float* be1 = (const float*)d_in[4];
  const float* We2 = (const float*)d_in[5];
  const float* be2 = (const float*)d_in[6];
  const float* Ww0 = (const float*)d_in[7],  *bw0 = (const float*)d_in[8];
  const float* Wb0 = (const float*)d_in[9],  *bb0 = (const float*)d_in[10];
  const float* Ws0 = (const float*)d_in[11], *bs0i = (const float*)d_in[12];
  const float* Ww1 = (const float*)d_in[13], *bw1 = (const float*)d_in[14];
  const float* Wb1 = (const float*)d_in[15], *bb1 = (const float*)d_in[16];
  const float* Ws1 = (const float*)d_in[17], *bs1i = (const float*)d_in[18];
  const float* Ww2 = (const float*)d_in[19], *bw2 = (const float*)d_in[20];
  const float* Wb2 = (const float*)d_in[21], *bb2 = (const float*)d_in[22];
  const float* Ws2 = (const float*)d_in[23], *bs2i = (const float*)d_in[24];

  char* ws = (char*)d_ws;
  size_t off = 0;
  auto alloc = [&](size_t bytes)->char*{
    char* p = ws + off; off += (bytes + 255) & ~(size_t)255; return p;
  };
  uint16_t* WpT0  = (uint16_t*)alloc((size_t)24576*KZ*2);  // 128 * 192 rows
  uint16_t* WpT1  = (uint16_t*)alloc((size_t)16384*KZ*2);
  uint16_t* WpT2  = (uint16_t*)alloc((size_t)512*KZ*2);
  uint16_t* We1T  = (uint16_t*)alloc((size_t)1024*KH*2);
  uint16_t* We2T  = (uint16_t*)alloc((size_t)1024*KZ*2);
  uint16_t* Wbs0T = (uint16_t*)alloc((size_t)256*KZ*2);    // contiguous with
  uint16_t* Wbs1T = (uint16_t*)alloc((size_t)256*KZ*2);    // Wbs0T (512 rows)
  uint16_t* Wbs2T = (uint16_t*)alloc((size_t)128*KZ*2);
  uint16_t* hinp  = (uint16_t*)alloc((size_t)B4*KH*2);
  uint16_t* z1p   = (uint16_t*)alloc((size_t)B4*KZ*2);
  uint16_t* zp    = (uint16_t*)alloc((size_t)B4*KZ*2);
  float*    bsb0  = (float*)alloc((size_t)256*B4*4);   // transposed [256][B4]
  float*    bsb1  = (float*)alloc((size_t)256*B4*4);   // contiguous with bsb0
  float*    bsb2  = (float*)alloc((size_t)B4*128*4);
  uint16_t* x0T   = (uint16_t*)alloc((size_t)192*B4*2);
  uint16_t* x1T   = (uint16_t*)alloc((size_t)128*B4*2);
  uint16_t* x2T   = (uint16_t*)alloc((size_t)128*B4*2);
  float*    w2    = (float*)alloc((size_t)B4*512*4);
  (void)ws_size; (void)in_sizes; (void)n_in; (void)out_size;
  (void)Wbs1T;

  hipMemsetAsync(Wbs2T, 0, (size_t)128*KZ*2, stream);

  dim3 blk(256);
  // ALL prep work in one launch (51201 blocks)
  mega_prep<<<dim3(51201),blk,0,stream>>>(
      Ww0, bw0, Ww1, bw1, Ww2, bw2, We1, be1, We2, be2,
      Wb0, bb0, Ws0, bs0i, Wb1, bb1, Ws1, bs1i, Wb2, bb2, Ws2, bs2i,
      obs, act, prefs,
      WpT0, WpT1, WpT2, We1T, We2T, Wbs0T, Wbs2T,
      hinp, x0T, z1p, zp);

  // z1 = relu(hin' @ We1')   [B,1024] bf16 into z1p (stride KZ)
  gemm128<1,1,0><<<dim3(32,8),blk,0,stream>>>(hinp, KH, We1T, KH, z1p, KZ, KH);
  // z = relu(z1' @ We2')     [B,1024] bf16 into zp (stride KZ)
  gemm128<1,1,0><<<dim3(32,8),blk,0,stream>>>(z1p, KZ, We2T, KZ, zp, KZ, KZ);
  // all head GEMMs (bsb0 TRANS, bsb2, w2) in one launch
  gemm_heads<<<dim3(32,9),blk,0,stream>>>(zp, Wbs0T, Wbs2T, WpT2, bsb0, bsb2, w2);

  // fused hyper layers 0 and 1: 1024 blocks (8 xcd * 64 pairs * 2 m-tiles)
  hyper2n<192><<<dim3(1024),dim3(512),0,stream>>>(zp, WpT0, x0T, bsb0, x1T, 1);
  hyper2n<128><<<dim3(1024),dim3(512),0,stream>>>(zp, WpT1, x1T, bsb1, x2T, 1);

  finalize_k<<<dim3(B4/64),blk,0,stream>>>(w2, x2T, bsb2, (float*)d_out);
}